// Round 1
// baseline (45.051 us; speedup 1.0000x reference)
//
#include <hip/hip_runtime.h>
#include <cmath>

#define NN 1024
#define FF 512
#define HH 64

// ---------------------------------------------------------------------------
// k1: h = relu(x@W1 + b1) @ W2 + b2 ; ei = h@Wa1[:H] ; ejb = h@Wa1[H:] + ba1
// 64 blocks x 256 threads, 16 rows per block.
// ---------------------------------------------------------------------------
__global__ __launch_bounds__(256) void k1_transform(
    const float* __restrict__ x, const float* __restrict__ W1,
    const float* __restrict__ b1, const float* __restrict__ W2,
    const float* __restrict__ b2, const float* __restrict__ Wa1,
    const float* __restrict__ ba1,
    float* __restrict__ ei, float* __restrict__ ejb)
{
    __shared__ float xs[16][516];   // pad 516: 516%32==4 -> banks (4r+k)%32
    __shared__ float ts[16][68];
    __shared__ float hs[16][68];
    const int tid = threadIdx.x;
    const int row0 = blockIdx.x * 16;

    // stage x tile [16][512]
    #pragma unroll
    for (int l = 0; l < 8; ++l) {
        int f4 = tid + l * 256;
        int r = f4 >> 7;             // 128 float4 per row
        int c = (f4 & 127) << 2;
        float4 v = *reinterpret_cast<const float4*>(x + (row0 + r) * FF + c);
        *reinterpret_cast<float4*>(&xs[r][c]) = v;
    }
    __syncthreads();

    const int r  = tid >> 4;         // 0..15 row
    const int cg = (tid & 15) << 2;  // col group of 4

    // GEMM1: t = relu(x @ W1 + b1)
    float4 acc = make_float4(0.f, 0.f, 0.f, 0.f);
    #pragma unroll 4
    for (int k = 0; k < FF; k += 4) {
        float4 a  = *reinterpret_cast<const float4*>(&xs[r][k]);
        float4 w0 = *reinterpret_cast<const float4*>(W1 + (k + 0) * HH + cg);
        float4 w1 = *reinterpret_cast<const float4*>(W1 + (k + 1) * HH + cg);
        float4 w2 = *reinterpret_cast<const float4*>(W1 + (k + 2) * HH + cg);
        float4 w3 = *reinterpret_cast<const float4*>(W1 + (k + 3) * HH + cg);
        acc.x += a.x * w0.x + a.y * w1.x + a.z * w2.x + a.w * w3.x;
        acc.y += a.x * w0.y + a.y * w1.y + a.z * w2.y + a.w * w3.y;
        acc.z += a.x * w0.z + a.y * w1.z + a.z * w2.z + a.w * w3.z;
        acc.w += a.x * w0.w + a.y * w1.w + a.z * w2.w + a.w * w3.w;
    }
    {
        float4 bv = *reinterpret_cast<const float4*>(b1 + cg);
        float4 t;
        t.x = fmaxf(acc.x + bv.x, 0.f);
        t.y = fmaxf(acc.y + bv.y, 0.f);
        t.z = fmaxf(acc.z + bv.z, 0.f);
        t.w = fmaxf(acc.w + bv.w, 0.f);
        *reinterpret_cast<float4*>(&ts[r][cg]) = t;
    }
    __syncthreads();

    // GEMM2: h = t @ W2 + b2
    float4 acc2 = make_float4(0.f, 0.f, 0.f, 0.f);
    #pragma unroll
    for (int k = 0; k < HH; k += 4) {
        float4 a  = *reinterpret_cast<const float4*>(&ts[r][k]);
        float4 w0 = *reinterpret_cast<const float4*>(W2 + (k + 0) * HH + cg);
        float4 w1 = *reinterpret_cast<const float4*>(W2 + (k + 1) * HH + cg);
        float4 w2 = *reinterpret_cast<const float4*>(W2 + (k + 2) * HH + cg);
        float4 w3 = *reinterpret_cast<const float4*>(W2 + (k + 3) * HH + cg);
        acc2.x += a.x * w0.x + a.y * w1.x + a.z * w2.x + a.w * w3.x;
        acc2.y += a.x * w0.y + a.y * w1.y + a.z * w2.y + a.w * w3.y;
        acc2.z += a.x * w0.z + a.y * w1.z + a.z * w2.z + a.w * w3.z;
        acc2.w += a.x * w0.w + a.y * w1.w + a.z * w2.w + a.w * w3.w;
    }
    {
        float4 bv = *reinterpret_cast<const float4*>(b2 + cg);
        float4 h;
        h.x = acc2.x + bv.x; h.y = acc2.y + bv.y;
        h.z = acc2.z + bv.z; h.w = acc2.w + bv.w;
        *reinterpret_cast<float4*>(&hs[r][cg]) = h;
    }
    __syncthreads();

    // GEMM3: ei = h @ Wa1[:H] ; ejb = h @ Wa1[H:] + ba1
    float4 ai = make_float4(0.f, 0.f, 0.f, 0.f);
    float4 aj = make_float4(0.f, 0.f, 0.f, 0.f);
    #pragma unroll
    for (int k = 0; k < HH; k += 4) {
        float4 a = *reinterpret_cast<const float4*>(&hs[r][k]);
        float4 t0 = *reinterpret_cast<const float4*>(Wa1 + (k + 0) * HH + cg);
        float4 t1 = *reinterpret_cast<const float4*>(Wa1 + (k + 1) * HH + cg);
        float4 t2 = *reinterpret_cast<const float4*>(Wa1 + (k + 2) * HH + cg);
        float4 t3 = *reinterpret_cast<const float4*>(Wa1 + (k + 3) * HH + cg);
        float4 u0 = *reinterpret_cast<const float4*>(Wa1 + (HH + k + 0) * HH + cg);
        float4 u1 = *reinterpret_cast<const float4*>(Wa1 + (HH + k + 1) * HH + cg);
        float4 u2 = *reinterpret_cast<const float4*>(Wa1 + (HH + k + 2) * HH + cg);
        float4 u3 = *reinterpret_cast<const float4*>(Wa1 + (HH + k + 3) * HH + cg);
        ai.x += a.x * t0.x + a.y * t1.x + a.z * t2.x + a.w * t3.x;
        ai.y += a.x * t0.y + a.y * t1.y + a.z * t2.y + a.w * t3.y;
        ai.z += a.x * t0.z + a.y * t1.z + a.z * t2.z + a.w * t3.z;
        ai.w += a.x * t0.w + a.y * t1.w + a.z * t2.w + a.w * t3.w;
        aj.x += a.x * u0.x + a.y * u1.x + a.z * u2.x + a.w * u3.x;
        aj.y += a.x * u0.y + a.y * u1.y + a.z * u2.y + a.w * u3.y;
        aj.z += a.x * u0.z + a.y * u1.z + a.z * u2.z + a.w * u3.z;
        aj.w += a.x * u0.w + a.y * u1.w + a.z * u2.w + a.w * u3.w;
    }
    {
        float4 bv = *reinterpret_cast<const float4*>(ba1 + cg);
        aj.x += bv.x; aj.y += bv.y; aj.z += bv.z; aj.w += bv.w;
        *reinterpret_cast<float4*>(ei  + (row0 + r) * HH + cg) = ai;
        *reinterpret_cast<float4*>(ejb + (row0 + r) * HH + cg) = aj;
    }
}

// ---------------------------------------------------------------------------
// k2: raw scores s(i,j) = sum_h relu(ei[i,h] + ejb[j,h]) * wa2[h]
// 256 blocks (16x16 grid of 64x64 tiles), 256 threads, 4x4 regs per thread.
// ---------------------------------------------------------------------------
__global__ __launch_bounds__(256) void k2_scores(
    const float* __restrict__ ei, const float* __restrict__ ejb,
    const float* __restrict__ wa2, float* __restrict__ sraw)
{
    __shared__ float eil[64][68];   // stride 68 -> banks (4*row + h) % 32
    __shared__ float ejl[64][68];
    __shared__ float wl[64];
    const int tid = threadIdx.x;
    const int bi = (blockIdx.x >> 4) * 64;
    const int bj = (blockIdx.x & 15) * 64;

    #pragma unroll
    for (int l = 0; l < 4; ++l) {
        int f4 = tid + l * 256;
        int r = f4 >> 4;             // 16 float4 per row
        int c = (f4 & 15) << 2;
        *reinterpret_cast<float4*>(&eil[r][c]) =
            *reinterpret_cast<const float4*>(ei + (bi + r) * HH + c);
        *reinterpret_cast<float4*>(&ejl[r][c]) =
            *reinterpret_cast<const float4*>(ejb + (bj + r) * HH + c);
    }
    if (tid < 16) {
        *reinterpret_cast<float4*>(&wl[tid * 4]) =
            *reinterpret_cast<const float4*>(wa2 + tid * 4);
    }
    __syncthreads();

    const int ty = tid >> 4;   // 0..15
    const int tx = tid & 15;   // 0..15
    float acc[4][4] = {};

    #pragma unroll
    for (int h = 0; h < HH; h += 4) {
        float4 w = *reinterpret_cast<const float4*>(&wl[h]);
        float4 A[4], B[4];
        #pragma unroll
        for (int d = 0; d < 4; ++d) {
            A[d] = *reinterpret_cast<const float4*>(&eil[ty + 16 * d][h]);
            B[d] = *reinterpret_cast<const float4*>(&ejl[tx + 16 * d][h]);
        }
        #pragma unroll
        for (int a = 0; a < 4; ++a) {
            #pragma unroll
            for (int b = 0; b < 4; ++b) {
                acc[a][b] += fmaxf(A[a].x + B[b].x, 0.f) * w.x
                           + fmaxf(A[a].y + B[b].y, 0.f) * w.y
                           + fmaxf(A[a].z + B[b].z, 0.f) * w.z
                           + fmaxf(A[a].w + B[b].w, 0.f) * w.w;
            }
        }
    }
    #pragma unroll
    for (int a = 0; a < 4; ++a) {
        #pragma unroll
        for (int b = 0; b < 4; ++b) {
            sraw[(bi + ty + 16 * a) * NN + (bj + tx + 16 * b)] = acc[a][b];
        }
    }
}

// ---------------------------------------------------------------------------
// k3: in-place symmetrize + bias/temp + sigmoid over tile pairs (I<=J),
// deterministic per-block partial sums of adjacency.
// 136 blocks x 256 threads.
// ---------------------------------------------------------------------------
__global__ __launch_bounds__(256) void k3_sym(
    float* __restrict__ s, const float* __restrict__ ba2,
    const float* __restrict__ temp, float* __restrict__ partials)
{
    __shared__ float A[64][65];
    __shared__ float B[64][65];
    __shared__ float wsum[4];
    const int tid = threadIdx.x;

    int I = 0, rem = blockIdx.x, rl = 16;
    while (rem >= rl) { rem -= rl; ++I; --rl; }
    const int J = I + rem;
    const int bi = I * 64, bj = J * 64;

    #pragma unroll
    for (int l = 0; l < 16; ++l) {
        int e = tid + l * 256;
        int r = e >> 6, c = e & 63;
        A[r][c] = s[(bi + r) * NN + bj + c];
        B[r][c] = s[(bj + r) * NN + bi + c];
    }
    __syncthreads();

    const float t = fminf(fmaxf(temp[0], 0.1f), 5.0f);
    const float invt = 1.0f / t;
    const float bb = ba2[0];

    float vals[16];
    float lsum = 0.f;
    #pragma unroll
    for (int l = 0; l < 16; ++l) {
        int e = tid + l * 256;
        int r = e >> 6, c = e & 63;
        float v = 0.5f * (A[r][c] + B[c][r]);
        v = (v + bb) * invt;
        float adj = 1.0f / (1.0f + expf(-v));
        vals[l] = adj;
        lsum += adj;
    }
    __syncthreads();

    // write tile (I,J); stash adjacency in A for transposed write
    #pragma unroll
    for (int l = 0; l < 16; ++l) {
        int e = tid + l * 256;
        int r = e >> 6, c = e & 63;
        s[(bi + r) * NN + bj + c] = vals[l];
        A[r][c] = vals[l];
    }
    if (I != J) {
        __syncthreads();
        #pragma unroll
        for (int l = 0; l < 16; ++l) {
            int e = tid + l * 256;
            int r = e >> 6, c = e & 63;
            s[(bj + r) * NN + bi + c] = A[c][r];
        }
    }

    // deterministic block reduction: fixed shuffle tree + fixed wave order
    float w = lsum;
    #pragma unroll
    for (int off = 32; off > 0; off >>= 1) w += __shfl_down(w, off);
    if ((tid & 63) == 0) wsum[tid >> 6] = w;
    __syncthreads();
    if (tid == 0) {
        float tot = (wsum[0] + wsum[1]) + (wsum[2] + wsum[3]);
        partials[blockIdx.x] = (I == J ? 1.0f : 2.0f) * tot;
    }
}

// ---------------------------------------------------------------------------
// k4: deterministic final reduction -> sparsity loss
// ---------------------------------------------------------------------------
__global__ void k4_reduce(const float* __restrict__ partials,
                          float* __restrict__ out)
{
    if (threadIdx.x == 0 && blockIdx.x == 0) {
        float sum = 0.f;
        for (int i = 0; i < 136; ++i) sum += partials[i];
        out[NN * NN] = 0.01f * sum / (float)(NN * NN);
    }
}

extern "C" void kernel_launch(void* const* d_in, const int* in_sizes, int n_in,
                              void* d_out, int out_size, void* d_ws, size_t ws_size,
                              hipStream_t stream)
{
    const float* x    = (const float*)d_in[0];
    const float* W1   = (const float*)d_in[1];
    const float* b1   = (const float*)d_in[2];
    const float* W2   = (const float*)d_in[3];
    const float* b2   = (const float*)d_in[4];
    const float* Wa1  = (const float*)d_in[5];
    const float* ba1  = (const float*)d_in[6];
    const float* wa2  = (const float*)d_in[7];
    const float* ba2  = (const float*)d_in[8];
    const float* temp = (const float*)d_in[9];
    float* out = (float*)d_out;

    float* ei    = (float*)d_ws;          // N*H floats
    float* ejb   = ei + NN * HH;          // N*H floats
    float* parts = ejb + NN * HH;         // 136 floats

    k1_transform<<<NN / 16, 256, 0, stream>>>(x, W1, b1, W2, b2, Wa1, ba1, ei, ejb);
    k2_scores<<<256, 256, 0, stream>>>(ei, ejb, wa2, out);
    k3_sym<<<136, 256, 0, stream>>>(out, ba2, temp, parts);
    k4_reduce<<<1, 64, 0, stream>>>(parts, out);
}

// Round 2
// 44.353 us; speedup vs baseline: 1.0157x; 1.0157x over previous
//
#include <hip/hip_runtime.h>
#include <cmath>

#define NN 1024
#define FF 512
#define HH 64

// ---------------------------------------------------------------------------
// k1: h = relu(x@W1 + b1) @ W2 + b2 ; ei = h@Wa1[:H] ; ejb = h@Wa1[H:] + ba1
// 64 blocks x 512 threads, 16 rows per block.
// GEMM1: k-split 2-way; GEMM2: k-split 2-way; GEMM3: ei/ejb split.
// Block 0 thread 0 also zeroes the arrival counter used by k3.
// ---------------------------------------------------------------------------
__global__ __launch_bounds__(512) void k1_transform(
    const float* __restrict__ x, const float* __restrict__ W1,
    const float* __restrict__ b1, const float* __restrict__ W2,
    const float* __restrict__ b2, const float* __restrict__ Wa1,
    const float* __restrict__ ba1,
    float* __restrict__ ei, float* __restrict__ ejb,
    int* __restrict__ counter)
{
    __shared__ float xs[16][516];      // 516%32==4 -> bank spread
    __shared__ float ts[16][68];
    __shared__ float hs[16][68];
    __shared__ float pp[2][16][68];    // k-split partials
    const int tid = threadIdx.x;
    const int row0 = blockIdx.x * 16;

    if (blockIdx.x == 0 && tid == 0) *counter = 0;   // visible to k3 via kernel boundary

    // stage x tile [16][512]: 2048 float4 / 512 threads = 4 each
    #pragma unroll
    for (int l = 0; l < 4; ++l) {
        int f4 = tid + l * 512;
        int r = f4 >> 7;
        int c = (f4 & 127) << 2;
        *reinterpret_cast<float4*>(&xs[r][c]) =
            *reinterpret_cast<const float4*>(x + (row0 + r) * FF + c);
    }
    __syncthreads();

    const int kh = tid >> 8;          // 0..1  (k-split half)
    const int r  = (tid >> 4) & 15;   // row 0..15
    const int cg = (tid & 15) << 2;   // col group of 4

    // GEMM1 partial: k in [kh*256, kh*256+256)
    {
        float4 acc = make_float4(0.f, 0.f, 0.f, 0.f);
        const int k0 = kh * 256;
        #pragma unroll 4
        for (int k = k0; k < k0 + 256; k += 4) {
            float4 a  = *reinterpret_cast<const float4*>(&xs[r][k]);
            float4 w0 = *reinterpret_cast<const float4*>(W1 + (k + 0) * HH + cg);
            float4 w1 = *reinterpret_cast<const float4*>(W1 + (k + 1) * HH + cg);
            float4 w2 = *reinterpret_cast<const float4*>(W1 + (k + 2) * HH + cg);
            float4 w3 = *reinterpret_cast<const float4*>(W1 + (k + 3) * HH + cg);
            acc.x += a.x * w0.x + a.y * w1.x + a.z * w2.x + a.w * w3.x;
            acc.y += a.x * w0.y + a.y * w1.y + a.z * w2.y + a.w * w3.y;
            acc.z += a.x * w0.z + a.y * w1.z + a.z * w2.z + a.w * w3.z;
            acc.w += a.x * w0.w + a.y * w1.w + a.z * w2.w + a.w * w3.w;
        }
        *reinterpret_cast<float4*>(&pp[kh][r][cg]) = acc;
    }
    __syncthreads();
    if (kh == 0) {
        float4 p0 = *reinterpret_cast<const float4*>(&pp[0][r][cg]);
        float4 p1 = *reinterpret_cast<const float4*>(&pp[1][r][cg]);
        float4 bv = *reinterpret_cast<const float4*>(b1 + cg);
        float4 t;
        t.x = fmaxf(p0.x + p1.x + bv.x, 0.f);
        t.y = fmaxf(p0.y + p1.y + bv.y, 0.f);
        t.z = fmaxf(p0.z + p1.z + bv.z, 0.f);
        t.w = fmaxf(p0.w + p1.w + bv.w, 0.f);
        *reinterpret_cast<float4*>(&ts[r][cg]) = t;
    }
    __syncthreads();

    // GEMM2 partial: k in [kh*32, kh*32+32)
    {
        float4 acc = make_float4(0.f, 0.f, 0.f, 0.f);
        const int k0 = kh * 32;
        #pragma unroll
        for (int k = k0; k < k0 + 32; k += 4) {
            float4 a  = *reinterpret_cast<const float4*>(&ts[r][k]);
            float4 w0 = *reinterpret_cast<const float4*>(W2 + (k + 0) * HH + cg);
            float4 w1 = *reinterpret_cast<const float4*>(W2 + (k + 1) * HH + cg);
            float4 w2 = *reinterpret_cast<const float4*>(W2 + (k + 2) * HH + cg);
            float4 w3 = *reinterpret_cast<const float4*>(W2 + (k + 3) * HH + cg);
            acc.x += a.x * w0.x + a.y * w1.x + a.z * w2.x + a.w * w3.x;
            acc.y += a.x * w0.y + a.y * w1.y + a.z * w2.y + a.w * w3.y;
            acc.z += a.x * w0.z + a.y * w1.z + a.z * w2.z + a.w * w3.z;
            acc.w += a.x * w0.w + a.y * w1.w + a.z * w2.w + a.w * w3.w;
        }
        __syncthreads();   // pp reuse
        *reinterpret_cast<float4*>(&pp[kh][r][cg]) = acc;
    }
    __syncthreads();
    if (kh == 0) {
        float4 p0 = *reinterpret_cast<const float4*>(&pp[0][r][cg]);
        float4 p1 = *reinterpret_cast<const float4*>(&pp[1][r][cg]);
        float4 bv = *reinterpret_cast<const float4*>(b2 + cg);
        float4 h;
        h.x = p0.x + p1.x + bv.x;
        h.y = p0.y + p1.y + bv.y;
        h.z = p0.z + p1.z + bv.z;
        h.w = p0.w + p1.w + bv.w;
        *reinterpret_cast<float4*>(&hs[r][cg]) = h;
    }
    __syncthreads();

    // GEMM3: kh==0 -> ei = h@Wa1[:H]; kh==1 -> ejb = h@Wa1[H:] + ba1
    {
        const float* Wb = Wa1 + kh * HH * HH;
        float4 acc = make_float4(0.f, 0.f, 0.f, 0.f);
        #pragma unroll
        for (int k = 0; k < HH; k += 4) {
            float4 a  = *reinterpret_cast<const float4*>(&hs[r][k]);
            float4 w0 = *reinterpret_cast<const float4*>(Wb + (k + 0) * HH + cg);
            float4 w1 = *reinterpret_cast<const float4*>(Wb + (k + 1) * HH + cg);
            float4 w2 = *reinterpret_cast<const float4*>(Wb + (k + 2) * HH + cg);
            float4 w3 = *reinterpret_cast<const float4*>(Wb + (k + 3) * HH + cg);
            acc.x += a.x * w0.x + a.y * w1.x + a.z * w2.x + a.w * w3.x;
            acc.y += a.x * w0.y + a.y * w1.y + a.z * w2.y + a.w * w3.y;
            acc.z += a.x * w0.z + a.y * w1.z + a.z * w2.z + a.w * w3.z;
            acc.w += a.x * w0.w + a.y * w1.w + a.z * w2.w + a.w * w3.w;
        }
        if (kh == 0) {
            *reinterpret_cast<float4*>(ei + (row0 + r) * HH + cg) = acc;
        } else {
            float4 bv = *reinterpret_cast<const float4*>(ba1 + cg);
            acc.x += bv.x; acc.y += bv.y; acc.z += bv.z; acc.w += bv.w;
            *reinterpret_cast<float4*>(ejb + (row0 + r) * HH + cg) = acc;
        }
    }
}

// ---------------------------------------------------------------------------
// k2: raw scores s(i,j) = sum_h relu(ei[i,h] + ejb[j,h]) * wa2[h]
// 512 blocks (16 x 32 grid of 64x32 tiles), 256 threads, 4x2 regs per thread.
// 2 blocks/CU -> 2 waves/SIMD for latency hiding.
// ---------------------------------------------------------------------------
__global__ __launch_bounds__(256) void k2_scores(
    const float* __restrict__ ei, const float* __restrict__ ejb,
    const float* __restrict__ wa2, float* __restrict__ sraw)
{
    __shared__ float eil[64][68];
    __shared__ float ejl[32][68];
    __shared__ float wl[64];
    const int tid = threadIdx.x;
    const int bi = (blockIdx.x >> 5) * 64;
    const int bj = (blockIdx.x & 31) * 32;

    #pragma unroll
    for (int l = 0; l < 4; ++l) {
        int f4 = tid + l * 256;
        int r = f4 >> 4;
        int c = (f4 & 15) << 2;
        *reinterpret_cast<float4*>(&eil[r][c]) =
            *reinterpret_cast<const float4*>(ei + (bi + r) * HH + c);
    }
    #pragma unroll
    for (int l = 0; l < 2; ++l) {
        int f4 = tid + l * 256;
        int r = f4 >> 4;
        int c = (f4 & 15) << 2;
        *reinterpret_cast<float4*>(&ejl[r][c]) =
            *reinterpret_cast<const float4*>(ejb + (bj + r) * HH + c);
    }
    if (tid < 16) {
        *reinterpret_cast<float4*>(&wl[tid * 4]) =
            *reinterpret_cast<const float4*>(wa2 + tid * 4);
    }
    __syncthreads();

    const int ty = tid >> 4;   // 0..15 -> rows ty+16a
    const int tx = tid & 15;   // 0..15 -> cols tx+16b
    float acc[4][2] = {};

    #pragma unroll
    for (int h = 0; h < HH; h += 4) {
        float4 w = *reinterpret_cast<const float4*>(&wl[h]);
        float4 A[4], B[2];
        #pragma unroll
        for (int d = 0; d < 4; ++d)
            A[d] = *reinterpret_cast<const float4*>(&eil[ty + 16 * d][h]);
        #pragma unroll
        for (int e = 0; e < 2; ++e)
            B[e] = *reinterpret_cast<const float4*>(&ejl[tx + 16 * e][h]);
        #pragma unroll
        for (int a = 0; a < 4; ++a) {
            #pragma unroll
            for (int b = 0; b < 2; ++b) {
                acc[a][b] += fmaxf(A[a].x + B[b].x, 0.f) * w.x
                           + fmaxf(A[a].y + B[b].y, 0.f) * w.y
                           + fmaxf(A[a].z + B[b].z, 0.f) * w.z
                           + fmaxf(A[a].w + B[b].w, 0.f) * w.w;
            }
        }
    }
    #pragma unroll
    for (int a = 0; a < 4; ++a)
        #pragma unroll
        for (int b = 0; b < 2; ++b)
            sraw[(bi + ty + 16 * a) * NN + (bj + tx + 16 * b)] = acc[a][b];
}

// ---------------------------------------------------------------------------
// k3: symmetrize + bias/temp + sigmoid over tile pairs (I<=J), in place.
// 136 blocks x 256 threads. Fused final reduction: last block (device-scope
// arrival counter) tree-sums the 136 partials in fixed order -> loss.
// ---------------------------------------------------------------------------
__global__ __launch_bounds__(256) void k3_sym(
    float* __restrict__ s, const float* __restrict__ ba2,
    const float* __restrict__ temp, float* __restrict__ partials,
    int* __restrict__ counter, float* __restrict__ out_loss)
{
    __shared__ float As[64][68];   // row-read tile (float4 stores ok, stride 68)
    __shared__ float Bt[64][69];   // transpose-read tile (scalar stores, stride 69)
    __shared__ float wsum[4];
    __shared__ int lastFlag;
    const int tid = threadIdx.x;

    int I = 0, rem = blockIdx.x, rl = 16;
    while (rem >= rl) { rem -= rl; ++I; --rl; }
    const int J = I + rem;
    const int bi = I * 64, bj = J * 64;

    // stage: As[r][c] = S[bi+r][bj+c];  Bt[cb][rb] = S[bj+rb][bi+cb]
    #pragma unroll
    for (int l = 0; l < 4; ++l) {
        int f4 = tid + l * 256;
        int rb = f4 >> 4;
        int cb = (f4 & 15) << 2;
        *reinterpret_cast<float4*>(&As[rb][cb]) =
            *reinterpret_cast<const float4*>(s + (bi + rb) * NN + bj + cb);
        float4 bv = *reinterpret_cast<const float4*>(s + (bj + rb) * NN + bi + cb);
        Bt[cb + 0][rb] = bv.x;
        Bt[cb + 1][rb] = bv.y;
        Bt[cb + 2][rb] = bv.z;
        Bt[cb + 3][rb] = bv.w;
    }
    __syncthreads();

    const float t = fminf(fmaxf(temp[0], 0.1f), 5.0f);
    const float invt = 1.0f / t;
    const float bb = ba2[0];

    float vals[16];
    float lsum = 0.f;
    #pragma unroll
    for (int l = 0; l < 16; ++l) {
        int r = (tid >> 6) + 4 * l;
        int c = tid & 63;
        // S[j][i] with (i,j)=(bi+r, bj+c) is Bt[r][c]
        float v = 0.5f * (As[r][c] + Bt[r][c]);
        v = (v + bb) * invt;
        float adj = 1.0f / (1.0f + expf(-v));
        vals[l] = adj;
        lsum += adj;
        s[(bi + r) * NN + bj + c] = adj;   // direct tile write, coalesced
    }
    __syncthreads();   // all Bt reads done

    if (I != J) {
        // stage adj transposed into Bt: Bt[c][r] = adj[r][c]
        #pragma unroll
        for (int l = 0; l < 16; ++l) {
            int r = (tid >> 6) + 4 * l;
            int c = tid & 63;
            Bt[c][r] = vals[l];
        }
        __syncthreads();
        // write transposed tile: S[bj+r][bi+c] = adj[c][r] = Bt[r][c]
        #pragma unroll
        for (int l = 0; l < 16; ++l) {
            int r = (tid >> 6) + 4 * l;
            int c = tid & 63;
            s[(bj + r) * NN + bi + c] = Bt[r][c];
        }
    }

    // deterministic per-block partial: fixed shuffle tree + fixed wave order
    float w = lsum;
    #pragma unroll
    for (int off = 32; off > 0; off >>= 1) w += __shfl_down(w, off);
    if ((tid & 63) == 0) wsum[tid >> 6] = w;
    __syncthreads();
    if (tid == 0) {
        float tot = (wsum[0] + wsum[1]) + (wsum[2] + wsum[3]);
        float val = (I == J ? 1.0f : 2.0f) * tot;
        atomicExch(&partials[blockIdx.x], val);   // device-coherent store
        __threadfence();
        int old = atomicAdd(counter, 1);
        lastFlag = (old == 135);
    }
    __syncthreads();

    if (lastFlag) {
        // last arriving block: fixed-order tree over 136 slots -> deterministic
        float v = (tid < 136) ? atomicAdd(&partials[tid], 0.0f) : 0.0f;
        #pragma unroll
        for (int off = 32; off > 0; off >>= 1) v += __shfl_down(v, off);
        if ((tid & 63) == 0) wsum[tid >> 6] = v;
        __syncthreads();
        if (tid == 0) {
            float tot = (wsum[0] + wsum[1]) + (wsum[2] + wsum[3]);
            *out_loss = 0.01f * tot / (float)(NN * NN);
        }
    }
}

extern "C" void kernel_launch(void* const* d_in, const int* in_sizes, int n_in,
                              void* d_out, int out_size, void* d_ws, size_t ws_size,
                              hipStream_t stream)
{
    const float* x    = (const float*)d_in[0];
    const float* W1   = (const float*)d_in[1];
    const float* b1   = (const float*)d_in[2];
    const float* W2   = (const float*)d_in[3];
    const float* b2   = (const float*)d_in[4];
    const float* Wa1  = (const float*)d_in[5];
    const float* ba1  = (const float*)d_in[6];
    const float* wa2  = (const float*)d_in[7];
    const float* ba2  = (const float*)d_in[8];
    const float* temp = (const float*)d_in[9];
    float* out = (float*)d_out;

    float* ei    = (float*)d_ws;          // N*H floats
    float* ejb   = ei + NN * HH;          // N*H floats
    float* parts = ejb + NN * HH;         // 136 floats
    int*   ctr   = (int*)(parts + 136);   // arrival counter

    k1_transform<<<NN / 16, 512, 0, stream>>>(x, W1, b1, W2, b2, Wa1, ba1, ei, ejb, ctr);
    k2_scores<<<512, 256, 0, stream>>>(ei, ejb, wa2, out);
    k3_sym<<<136, 256, 0, stream>>>(out, ba2, temp, parts, ctr, out + NN * NN);
}